// Round 4
// baseline (192.016 us; speedup 1.0000x reference)
//
#include <hip/hip_runtime.h>
#include <hip/hip_bf16.h>
#include <math.h>

// Problem constants (fixed by reference setup_inputs)
#define BN 8192       // batch
#define DK 256        // embedding dim (= GEMM K)
#define TM 128        // row/col tile
#define NSLICE 8      // column slices (grid y)
#define SLICE_TILES 8 // 8 x 128 cols = 1024 cols per slice
#define NBLOCKS 512   // contrast grid size
#define INV_T 1.42857142857142857f    // 1/0.7, also the fixed softmax shift m
#define C_EXP2 2.0609929155556620f    // (1/0.7)*log2(e): exp((v-1)/T)=exp2((v-1)*C_EXP2)

using bf16x8 = __attribute__((ext_vector_type(8))) short;  // 8 bf16 = 4 VGPRs
using f32x4  = __attribute__((ext_vector_type(4))) float;

__device__ __forceinline__ void async_copy16(void* lds, const void* g) {
  __builtin_amdgcn_global_load_lds(
      (const __attribute__((address_space(1))) unsigned int*)g,
      (__attribute__((address_space(3))) unsigned int*)lds,
      16, 0, 0);
}

// ---------------- Kernel 1: L2-normalize rows, fp32 -> bf16 ----------------
// One wave per row: float4 loads, shuffle reduce, ushort4 stores. No LDS.
// Block 0 thread 0 also zeroes the ticket counter (ws is re-poisoned 0xAA
// before every launch); visible to kernel 2 via stream ordering.
__global__ void norm_kernel(const float* __restrict__ E,
                            unsigned short* __restrict__ Eb,
                            unsigned int* __restrict__ ticket) {
  if (blockIdx.x == 0 && threadIdx.x == 0) *ticket = 0u;
  const int wv = threadIdx.x >> 6, lane = threadIdx.x & 63;
  const int row = blockIdx.x * 4 + wv;
  const float4 x = *(const float4*)&E[(size_t)row * DK + lane * 4];
  float ss = x.x * x.x + x.y * x.y + x.z * x.z + x.w * x.w;
#pragma unroll
  for (int m = 1; m < 64; m <<= 1) ss += __shfl_xor(ss, m);
  const float scale = 1.0f / fmaxf(sqrtf(ss), 1e-12f);
  ushort4 o;
  __hip_bfloat16 h0 = __float2bfloat16(x.x * scale); o.x = *(unsigned short*)&h0;
  __hip_bfloat16 h1 = __float2bfloat16(x.y * scale); o.y = *(unsigned short*)&h1;
  __hip_bfloat16 h2 = __float2bfloat16(x.z * scale); o.z = *(unsigned short*)&h2;
  __hip_bfloat16 h3 = __float2bfloat16(x.w * scale); o.w = *(unsigned short*)&h3;
  *(ushort4*)&Eb[(size_t)row * DK + lane * 4] = o;
}

// ---------------- Kernel 2: fused sims + masked max/sum-exp + finalize ------
// Block = 256 thr (4 waves, 2x2 of 64x64 wave tiles), rows [bx*128,+128) vs
// cols [by*1024,+1024). A persistent in LDS (64 KB), B staged in BK=64 chunks
// (16 KB). LDS = 80 KB -> 2 blocks/CU.
// XOR swizzle at 16B-chunk granularity breaks the 16-way bank conflict of the
// power-of-2 row strides (512B/128B) while keeping global_load_lds's
// lane-contiguous-LDS constraint.
// The LAST block (atomic ticket) reduces all row partials and writes out[0]
// (release/acquire via __threadfence) — saves 2-3 dispatch boundaries.
__launch_bounds__(256, 2)
__global__ void contrast_kernel(const unsigned short* __restrict__ Eb,
                                const int* __restrict__ cat,
                                float* __restrict__ posPart,
                                float* __restrict__ negPart,
                                unsigned int* __restrict__ ticket,
                                float* __restrict__ out) {
  __shared__ __align__(16) unsigned short As[TM * DK];  // 64 KB, [row][k] swizzled
  __shared__ __align__(16) unsigned short Bs[TM * 64];  // 16 KB, [col][k-chunk] swizzled

  const int tid = threadIdx.x;
  const int lane = tid & 63;
  const int wv = tid >> 6;
  const int wm = wv >> 1;      // wave row (0..1)
  const int wn = wv & 1;       // wave col (0..1)
  const int quad = lane >> 4;
  const int l16 = lane & 15;
  const int sw = l16 & 7;      // per-lane swizzle key (row&7 == l16&7)
  const int rowBase = blockIdx.x * TM;
  const int colBase0 = blockIdx.y * (TM * SLICE_TILES);

  // ---- stage A tile: 64 KB, swizzled source ----
  {
    const char* gbase = (const char*)(Eb + (size_t)rowBase * DK);
#pragma unroll
    for (int i = 0; i < 16; ++i) {
      const int chunk = tid + i * 256;   // LDS 16B-chunk index (lane-contiguous)
      const int row = chunk >> 5;        // 32 chunks per 512B row
      const int c = chunk & 31;
      async_copy16((char*)As + chunk * 16,
                   gbase + row * 512 + (c ^ (row & 7)) * 16);
    }
  }

  // Rows owned by this lane (C layout: col=lane&15, row=quad*4+reg):
  int rowIdx[16];
  int catRow[16];
  float posmx[16], negsm[16];
#pragma unroll
  for (int ti = 0; ti < 4; ++ti)
#pragma unroll
    for (int r = 0; r < 4; ++r) {
      const int si = ti * 4 + r;
      rowIdx[si] = rowBase + wm * 64 + ti * 16 + quad * 4 + r;
      catRow[si] = cat[rowIdx[si]];
      posmx[si] = -1e30f;
      negsm[si] = 0.0f;
    }

#pragma unroll 1
  for (int ct = 0; ct < SLICE_TILES; ++ct) {
    const int colBase = colBase0 + ct * TM;

    f32x4 acc[4][4];
#pragma unroll
    for (int ti = 0; ti < 4; ++ti)
#pragma unroll
      for (int tj = 0; tj < 4; ++tj)
        acc[ti][tj] = f32x4{0.f, 0.f, 0.f, 0.f};

#pragma unroll 1
    for (int kc = 0; kc < 4; ++kc) {
      __syncthreads();  // prev Bs consumers done (first iter: covers A wait)
      {
        const int col8 = tid >> 3;   // col within tile (+32 per it)
        const int c = tid & 7;       // 16B chunk within 128B k-slab
        const char* g = (const char*)Eb +
                        (size_t)(colBase + col8) * 512 +
                        kc * 128 + ((c ^ (col8 & 7)) * 16);
        char* l = (char*)Bs + tid * 16;
#pragma unroll
        for (int it = 0; it < 4; ++it)   // col8+32: (col8&7) unchanged
          async_copy16(l + it * 4096, g + (size_t)it * 32 * 512);
      }
      __syncthreads();  // Bs ready (barrier drains vmcnt)

#pragma unroll
      for (int s = 0; s < 2; ++s) {
        bf16x8 a[4], b[4];
#pragma unroll
        for (int ti = 0; ti < 4; ++ti)
          a[ti] = *(const bf16x8*)&As[(wm * 64 + ti * 16 + l16) * DK +
                                      (((kc * 8 + s * 4 + quad) ^ sw) << 3)];
#pragma unroll
        for (int tj = 0; tj < 4; ++tj)
          b[tj] = *(const bf16x8*)&Bs[(wn * 64 + tj * 16 + l16) * 64 +
                                      (((s * 4 + quad) ^ sw) << 3)];
#pragma unroll
        for (int ti = 0; ti < 4; ++ti)
#pragma unroll
          for (int tj = 0; tj < 4; ++tj)
            acc[ti][tj] = __builtin_amdgcn_mfma_f32_16x16x32_bf16(a[ti], b[tj], acc[ti][tj], 0, 0, 0);
      }
    }

    // ---- fused epilogue for this 128x128 tile (acc = raw cosines) ----
    int catCol[4], colIdx[4];
#pragma unroll
    for (int tj = 0; tj < 4; ++tj) {
      colIdx[tj] = colBase + wn * 64 + tj * 16 + l16;
      catCol[tj] = cat[colIdx[tj]];
    }
    if (colBase == rowBase) {
      // diagonal tile (1 of 64): self-exclusion needed
#pragma unroll
      for (int ti = 0; ti < 4; ++ti)
#pragma unroll
        for (int r = 0; r < 4; ++r) {
          const int si = ti * 4 + r;
          float pm = posmx[si];
          float ns = negsm[si];
#pragma unroll
          for (int tj = 0; tj < 4; ++tj) {
            const float v = acc[ti][tj][r];
            const bool same = (catRow[si] == catCol[tj]);
            const bool self = (rowIdx[si] == colIdx[tj]);
            const float e = exp2f(__fmaf_rn(v, C_EXP2, -C_EXP2));
            ns += same ? 0.0f : e;
            pm = (same && !self) ? fmaxf(pm, v) : pm;
          }
          posmx[si] = pm;
          negsm[si] = ns;
        }
    } else {
      // off-diagonal: no self possible
#pragma unroll
      for (int ti = 0; ti < 4; ++ti)
#pragma unroll
        for (int r = 0; r < 4; ++r) {
          const int si = ti * 4 + r;
          float pm = posmx[si];
          float ns = negsm[si];
#pragma unroll
          for (int tj = 0; tj < 4; ++tj) {
            const float v = acc[ti][tj][r];
            const bool same = (catRow[si] == catCol[tj]);
            const float e = exp2f(__fmaf_rn(v, C_EXP2, -C_EXP2));
            ns += same ? 0.0f : e;
            pm = same ? fmaxf(pm, v) : pm;
          }
          posmx[si] = pm;
          negsm[si] = ns;
        }
    }
  }

  // ---- reduce across the 16 lanes sharing each row (cols split) ----
#pragma unroll
  for (int si = 0; si < 16; ++si) {
    float pm = posmx[si], ns = negsm[si];
#pragma unroll
    for (int m = 1; m < 16; m <<= 1) {
      pm = fmaxf(pm, __shfl_xor(pm, m));
      ns += __shfl_xor(ns, m);
    }
    posmx[si] = pm;
    negsm[si] = ns;
  }

  // ---- combine the wn=0 / wn=1 wave halves via LDS (reuse As) ----
  float* red = (float*)As;  // [0..127]=pos, [128..255]=neg
  __syncthreads();
  if (wn == 1 && l16 == 0) {
#pragma unroll
    for (int si = 0; si < 16; ++si) {
      const int rl = wm * 64 + (si >> 2) * 16 + quad * 4 + (si & 3);
      red[rl] = posmx[si];
      red[128 + rl] = negsm[si];
    }
  }
  __syncthreads();
  if (wn == 0 && l16 == 0) {
#pragma unroll
    for (int si = 0; si < 16; ++si) {
      const int rl = wm * 64 + (si >> 2) * 16 + quad * 4 + (si & 3);
      const float pm = fmaxf(posmx[si], red[rl]);
      const float ns = negsm[si] + red[128 + rl];
      posPart[(size_t)(rowBase + rl) * NSLICE + blockIdx.y] = pm;  // raw cos max
      negPart[(size_t)(rowBase + rl) * NSLICE + blockIdx.y] = ns;
    }
  }

  // ---- ticket: last block to finish reduces everything ----
  __threadfence();            // release: partials visible device-wide
  __syncthreads();            // all lanes' writes + fences done (red reads done)
  unsigned int* flag = (unsigned int*)As;  // reuse LDS
  if (tid == 0) *flag = atomicAdd(ticket, 1u);
  __syncthreads();
  if (*flag == NBLOCKS - 1) {
    __threadfence();          // acquire: see all other blocks' partials
    float loss = 0.0f, c = 0.0f;
    for (int row = tid; row < BN; row += 256) {
      const float4 p0 = *(const float4*)&posPart[row * NSLICE];
      const float4 p1 = *(const float4*)&posPart[row * NSLICE + 4];
      const float4 n0 = *(const float4*)&negPart[row * NSLICE];
      const float4 n1 = *(const float4*)&negPart[row * NSLICE + 4];
      const float pm = fmaxf(fmaxf(fmaxf(p0.x, p0.y), fmaxf(p0.z, p0.w)),
                             fmaxf(fmaxf(p1.x, p1.y), fmaxf(p1.z, p1.w)));
      const float ns = (n0.x + n0.y + n0.z + n0.w) + (n1.x + n1.y + n1.z + n1.w);
      if (pm > -1e29f && ns > 0.0f) {   // valid: has positive AND negative
        const float pos = pm * INV_T;
        const float lse = INV_T + logf(expf(pos - INV_T) + ns);
        loss += lse - pos;
        c += 1.0f;
      }
    }
#pragma unroll
    for (int m = 1; m < 64; m <<= 1) {
      loss += __shfl_xor(loss, m);
      c += __shfl_xor(c, m);
    }
    float* sred = (float*)As + 16;  // past the flag
    if (lane == 0) { sred[wv] = loss; sred[4 + wv] = c; }
    __syncthreads();
    if (tid == 0) {
      const float T = sred[0] + sred[1] + sred[2] + sred[3];
      const float C = sred[4] + sred[5] + sred[6] + sred[7];
      out[0] = (C > 0.0f) ? T / C : 0.0f;
    }
  }
}

extern "C" void kernel_launch(void* const* d_in, const int* in_sizes, int n_in,
                              void* d_out, int out_size, void* d_ws, size_t ws_size,
                              hipStream_t stream) {
  const float* E = (const float*)d_in[0];
  const int* cat = (const int*)d_in[1];
  // d_in[2] (font_labels) unused by the reference.

  // Workspace: [0,4MB) bf16 normalized embeddings; partials; ticket.
  unsigned short* Eb = (unsigned short*)d_ws;
  float* posPart = (float*)((char*)d_ws + (size_t)BN * DK * 2);
  float* negPart = posPart + (size_t)BN * NSLICE;
  unsigned int* ticket = (unsigned int*)(negPart + (size_t)BN * NSLICE);
  float* out = (float*)d_out;

  hipLaunchKernelGGL(norm_kernel, dim3(BN / 4), dim3(256), 0, stream, E, Eb, ticket);
  hipLaunchKernelGGL(contrast_kernel, dim3(BN / TM, NSLICE), dim3(256), 0, stream,
                     Eb, cat, posPart, negPart, ticket, out);
}

// Round 5
// 176.752 us; speedup vs baseline: 1.0864x; 1.0864x over previous
//
#include <hip/hip_runtime.h>
#include <hip/hip_bf16.h>
#include <math.h>

// Problem constants (fixed by reference setup_inputs)
#define BN 8192       // batch
#define DK 256        // embedding dim (= GEMM K)
#define TM 128        // row/col tile
#define NSLICE 8      // column slices (grid y)
#define SLICE_TILES 8 // 8 x 128 cols = 1024 cols per slice
#define NBLOCKS 512   // contrast grid size
#define INV_T 1.42857142857142857f    // 1/0.7, also the fixed softmax shift m
#define C_EXP2 2.0609929155556620f    // (1/0.7)*log2(e): exp((v-1)/T)=exp2((v-1)*C_EXP2)

using bf16x8 = __attribute__((ext_vector_type(8))) short;  // 8 bf16 = 4 VGPRs
using f32x4  = __attribute__((ext_vector_type(4))) float;

__device__ __forceinline__ void async_copy16(void* lds, const void* g) {
  __builtin_amdgcn_global_load_lds(
      (const __attribute__((address_space(1))) unsigned int*)g,
      (__attribute__((address_space(3))) unsigned int*)lds,
      16, 0, 0);
}

// ---------------- Kernel 1: L2-normalize rows, fp32 -> bf16 ----------------
// One wave per row: float4 loads, shuffle reduce, ushort4 stores. No LDS.
// Block 0 thread 0 also zeroes the ticket counter; visible to kernel 2 via
// the kernel-boundary release (stream ordering).
__global__ void norm_kernel(const float* __restrict__ E,
                            unsigned short* __restrict__ Eb,
                            unsigned int* __restrict__ ticket) {
  if (blockIdx.x == 0 && threadIdx.x == 0) *ticket = 0u;
  const int wv = threadIdx.x >> 6, lane = threadIdx.x & 63;
  const int row = blockIdx.x * 4 + wv;
  const float4 x = *(const float4*)&E[(size_t)row * DK + lane * 4];
  float ss = x.x * x.x + x.y * x.y + x.z * x.z + x.w * x.w;
#pragma unroll
  for (int m = 1; m < 64; m <<= 1) ss += __shfl_xor(ss, m);
  const float scale = 1.0f / fmaxf(sqrtf(ss), 1e-12f);
  ushort4 o;
  __hip_bfloat16 h0 = __float2bfloat16(x.x * scale); o.x = *(unsigned short*)&h0;
  __hip_bfloat16 h1 = __float2bfloat16(x.y * scale); o.y = *(unsigned short*)&h1;
  __hip_bfloat16 h2 = __float2bfloat16(x.z * scale); o.z = *(unsigned short*)&h2;
  __hip_bfloat16 h3 = __float2bfloat16(x.w * scale); o.w = *(unsigned short*)&h3;
  *(ushort4*)&Eb[(size_t)row * DK + lane * 4] = o;
}

// ---------------- Kernel 2: fused sims + masked max/sum-exp + finalize ------
// Round-2 core (57.7us measured) + fence-FREE last-block finalize:
//  - partials stored via relaxed AGENT-scope atomic stores (global_store sc1,
//    write-through to device coherence point — NO buffer_wbl2/inv, which was
//    round 4's 2.4x regression: 512 blocks flushing L2 mid-flight evicted the
//    4MB Eb working set, WRITE_SIZE 512KB->3.6MB fingerprint)
//  - s_waitcnt vmcnt(0) + barrier orders stores before the ticket atomicAdd
//  - winner block reads partials via relaxed AGENT-scope atomic loads
//    (cache-bypassing, no invalidate), writes out[0].
__launch_bounds__(256, 2)
__global__ void contrast_kernel(const unsigned short* __restrict__ Eb,
                                const int* __restrict__ cat,
                                float* __restrict__ posPart,
                                float* __restrict__ negPart,
                                unsigned int* __restrict__ ticket,
                                float* __restrict__ out) {
  __shared__ __align__(16) unsigned short As[TM * DK];  // 64 KB, [row][k] swizzled
  __shared__ __align__(16) unsigned short Bs[TM * 64];  // 16 KB, [col][k-chunk] swizzled

  const int tid = threadIdx.x;
  const int lane = tid & 63;
  const int wv = tid >> 6;
  const int wm = wv >> 1;      // wave row (0..1)
  const int wn = wv & 1;       // wave col (0..1)
  const int quad = lane >> 4;
  const int l16 = lane & 15;
  const int sw = l16 & 7;      // per-lane swizzle key (row&7 == l16&7)
  const int rowBase = blockIdx.x * TM;
  const int colBase0 = blockIdx.y * (TM * SLICE_TILES);

  // ---- stage A tile: 64 KB, swizzled source ----
  {
    const char* gbase = (const char*)(Eb + (size_t)rowBase * DK);
#pragma unroll
    for (int i = 0; i < 16; ++i) {
      const int chunk = tid + i * 256;   // LDS 16B-chunk index (lane-contiguous)
      const int row = chunk >> 5;        // 32 chunks per 512B row
      const int c = chunk & 31;
      async_copy16((char*)As + chunk * 16,
                   gbase + row * 512 + (c ^ (row & 7)) * 16);
    }
  }

  // Rows owned by this lane (C layout: col=lane&15, row=quad*4+reg):
  int rowIdx[16];
  int catRow[16];
  float posmx[16], negsm[16];
#pragma unroll
  for (int ti = 0; ti < 4; ++ti)
#pragma unroll
    for (int r = 0; r < 4; ++r) {
      const int si = ti * 4 + r;
      rowIdx[si] = rowBase + wm * 64 + ti * 16 + quad * 4 + r;
      catRow[si] = cat[rowIdx[si]];
      posmx[si] = -1e30f;
      negsm[si] = 0.0f;
    }

#pragma unroll 1
  for (int ct = 0; ct < SLICE_TILES; ++ct) {
    const int colBase = colBase0 + ct * TM;

    f32x4 acc[4][4];
#pragma unroll
    for (int ti = 0; ti < 4; ++ti)
#pragma unroll
      for (int tj = 0; tj < 4; ++tj)
        acc[ti][tj] = f32x4{0.f, 0.f, 0.f, 0.f};

#pragma unroll 1
    for (int kc = 0; kc < 4; ++kc) {
      __syncthreads();  // prev Bs consumers done (first iter: covers A wait)
      {
        const int col8 = tid >> 3;   // col within tile (+32 per it)
        const int c = tid & 7;       // 16B chunk within 128B k-slab
        const char* g = (const char*)Eb +
                        (size_t)(colBase + col8) * 512 +
                        kc * 128 + ((c ^ (col8 & 7)) * 16);
        char* l = (char*)Bs + tid * 16;
#pragma unroll
        for (int it = 0; it < 4; ++it)   // col8+32: (col8&7) unchanged
          async_copy16(l + it * 4096, g + (size_t)it * 32 * 512);
      }
      __syncthreads();  // Bs ready (barrier drains vmcnt)

#pragma unroll
      for (int s = 0; s < 2; ++s) {
        bf16x8 a[4], b[4];
#pragma unroll
        for (int ti = 0; ti < 4; ++ti)
          a[ti] = *(const bf16x8*)&As[(wm * 64 + ti * 16 + l16) * DK +
                                      (((kc * 8 + s * 4 + quad) ^ sw) << 3)];
#pragma unroll
        for (int tj = 0; tj < 4; ++tj)
          b[tj] = *(const bf16x8*)&Bs[(wn * 64 + tj * 16 + l16) * 64 +
                                      (((s * 4 + quad) ^ sw) << 3)];
#pragma unroll
        for (int ti = 0; ti < 4; ++ti)
#pragma unroll
          for (int tj = 0; tj < 4; ++tj)
            acc[ti][tj] = __builtin_amdgcn_mfma_f32_16x16x32_bf16(a[ti], b[tj], acc[ti][tj], 0, 0, 0);
      }
    }

    // ---- fused epilogue for this 128x128 tile (acc = raw cosines) ----
    int catCol[4], colIdx[4];
#pragma unroll
    for (int tj = 0; tj < 4; ++tj) {
      colIdx[tj] = colBase + wn * 64 + tj * 16 + l16;
      catCol[tj] = cat[colIdx[tj]];
    }
#pragma unroll
    for (int ti = 0; ti < 4; ++ti)
#pragma unroll
      for (int r = 0; r < 4; ++r) {
        const int si = ti * 4 + r;
        float pm = posmx[si];
        float ns = negsm[si];
#pragma unroll
        for (int tj = 0; tj < 4; ++tj) {
          const float v = acc[ti][tj][r];
          const bool same = (catRow[si] == catCol[tj]);
          const bool self = (rowIdx[si] == colIdx[tj]);
          const float e = exp2f(__fmaf_rn(v, C_EXP2, -C_EXP2));
          ns += same ? 0.0f : e;
          pm = (same && !self) ? fmaxf(pm, v) : pm;
        }
        posmx[si] = pm;
        negsm[si] = ns;
      }
  }

  // ---- reduce across the 16 lanes sharing each row (cols split) ----
#pragma unroll
  for (int si = 0; si < 16; ++si) {
    float pm = posmx[si], ns = negsm[si];
#pragma unroll
    for (int m = 1; m < 16; m <<= 1) {
      pm = fmaxf(pm, __shfl_xor(pm, m));
      ns += __shfl_xor(ns, m);
    }
    posmx[si] = pm;
    negsm[si] = ns;
  }

  // ---- combine the wn=0 / wn=1 wave halves via LDS (reuse As) ----
  float* red = (float*)As;  // [0..127]=pos, [128..255]=neg
  __syncthreads();
  if (wn == 1 && l16 == 0) {
#pragma unroll
    for (int si = 0; si < 16; ++si) {
      const int rl = wm * 64 + (si >> 2) * 16 + quad * 4 + (si & 3);
      red[rl] = posmx[si];
      red[128 + rl] = negsm[si];
    }
  }
  __syncthreads();
  if (wn == 0 && l16 == 0) {
#pragma unroll
    for (int si = 0; si < 16; ++si) {
      const int rl = wm * 64 + (si >> 2) * 16 + quad * 4 + (si & 3);
      const float pm = fmaxf(posmx[si], red[rl]);
      const float ns = negsm[si] + red[128 + rl];
      // AGENT-scope relaxed stores: write-through to coherence point, no flush
      __hip_atomic_store(&posPart[(size_t)(rowBase + rl) * NSLICE + blockIdx.y],
                         pm, __ATOMIC_RELAXED, __HIP_MEMORY_SCOPE_AGENT);
      __hip_atomic_store(&negPart[(size_t)(rowBase + rl) * NSLICE + blockIdx.y],
                         ns, __ATOMIC_RELAXED, __HIP_MEMORY_SCOPE_AGENT);
    }
  }

  // ---- ticket: last block to finish reduces everything (fence-free) ----
  asm volatile("s_waitcnt vmcnt(0)" ::: "memory");  // own stores at coherence pt
  __syncthreads();                                  // all threads' stores drained
  unsigned int* flag = (unsigned int*)As;           // reuse LDS
  if (tid == 0) *flag = atomicAdd(ticket, 1u);      // device-scope RMW
  __syncthreads();
  if (*flag == NBLOCKS - 1) {
    float loss = 0.0f, c = 0.0f;
    for (int row = tid; row < BN; row += 256) {
      float pm = -1e30f, ns = 0.0f;
#pragma unroll
      for (int s = 0; s < NSLICE; ++s) {
        pm = fmaxf(pm, __hip_atomic_load(&posPart[(size_t)row * NSLICE + s],
                                         __ATOMIC_RELAXED, __HIP_MEMORY_SCOPE_AGENT));
        ns += __hip_atomic_load(&negPart[(size_t)row * NSLICE + s],
                                __ATOMIC_RELAXED, __HIP_MEMORY_SCOPE_AGENT);
      }
      if (pm > -1e29f && ns > 0.0f) {   // valid: has positive AND negative
        const float pos = pm * INV_T;
        const float lse = INV_T + logf(expf(pos - INV_T) + ns);
        loss += lse - pos;
        c += 1.0f;
      }
    }
#pragma unroll
    for (int m = 1; m < 64; m <<= 1) {
      loss += __shfl_xor(loss, m);
      c += __shfl_xor(c, m);
    }
    float* sred = (float*)As + 16;  // past the flag
    if (lane == 0) { sred[wv] = loss; sred[4 + wv] = c; }
    __syncthreads();
    if (tid == 0) {
      const float T = sred[0] + sred[1] + sred[2] + sred[3];
      const float C = sred[4] + sred[5] + sred[6] + sred[7];
      out[0] = (C > 0.0f) ? T / C : 0.0f;
    }
  }
}

extern "C" void kernel_launch(void* const* d_in, const int* in_sizes, int n_in,
                              void* d_out, int out_size, void* d_ws, size_t ws_size,
                              hipStream_t stream) {
  const float* E = (const float*)d_in[0];
  const int* cat = (const int*)d_in[1];
  // d_in[2] (font_labels) unused by the reference.

  // Workspace: [0,4MB) bf16 normalized embeddings; partials; ticket.
  unsigned short* Eb = (unsigned short*)d_ws;
  float* posPart = (float*)((char*)d_ws + (size_t)BN * DK * 2);
  float* negPart = posPart + (size_t)BN * NSLICE;
  unsigned int* ticket = (unsigned int*)(negPart + (size_t)BN * NSLICE);
  float* out = (float*)d_out;

  hipLaunchKernelGGL(norm_kernel, dim3(BN / 4), dim3(256), 0, stream, E, Eb, ticket);
  hipLaunchKernelGGL(contrast_kernel, dim3(BN / TM, NSLICE), dim3(256), 0, stream,
                     Eb, cat, posPart, negPart, ticket, out);
}